// Round 1
// baseline (273.355 us; speedup 1.0000x reference)
//
#include <hip/hip_runtime.h>
#include <hip/hip_bf16.h>

typedef __attribute__((ext_vector_type(8))) short short8;
typedef __attribute__((ext_vector_type(4))) float f32x4;

#define B_N 1024
#define D_K 512
#define C_N 100000
#define SCALE_F 64.0f
#define MARGIN_F 0.35f
#define BM 128
#define BN 128
#define BK 32
#define NT_ 782   // ceil(100000/128)

__device__ __forceinline__ float dot4(float4 a, float4 b) {
    return a.x * b.x + a.y * b.y + a.z * b.z + a.w * b.w;
}

// round-to-nearest-even f32 -> bf16 bits
__device__ __forceinline__ ushort f2b(float f) {
    unsigned int u = __float_as_uint(f);
    u = (u + 0x7FFFu + ((u >> 16) & 1u)) >> 16;
    return (ushort)u;
}

// ---------------- kernel A: normalize x rows -> f32 + bf16 ----------------
__global__ void norm_x_kernel(const float* __restrict__ x,
                              float* __restrict__ xn,
                              ushort* __restrict__ xnb) {
    int row = blockIdx.x * 4 + (threadIdx.x >> 6);
    int l = threadIdx.x & 63;
    const float4* rp = (const float4*)(x + (size_t)row * D_K);
    float4 a = rp[l], b = rp[64 + l];
    float ssq = dot4(a, a) + dot4(b, b);
#pragma unroll
    for (int m = 1; m < 64; m <<= 1) ssq += __shfl_xor(ssq, m);
    float inv = 1.0f / fmaxf(sqrtf(ssq), 1e-12f);
    a.x *= inv; a.y *= inv; a.z *= inv; a.w *= inv;
    b.x *= inv; b.y *= inv; b.z *= inv; b.w *= inv;
    float4* op = (float4*)(xn + (size_t)row * D_K);
    op[l] = a; op[64 + l] = b;
    ushort4 ua; ua.x = f2b(a.x); ua.y = f2b(a.y); ua.z = f2b(a.z); ua.w = f2b(a.w);
    ushort4 ub; ub.x = f2b(b.x); ub.y = f2b(b.y); ub.z = f2b(b.z); ub.w = f2b(b.w);
    ushort4* obp = (ushort4*)(xnb + (size_t)row * D_K);
    obp[l] = ua; obp[64 + l] = ub;
}

// ---------------- kernel B: normalize id_agent rows -> bf16 ----------------
__global__ void norm_w_kernel(const float* __restrict__ w,
                              ushort* __restrict__ wb) {
    int row = blockIdx.x * 4 + (threadIdx.x >> 6);
    int l = threadIdx.x & 63;
    const float4* rp = (const float4*)(w + (size_t)row * D_K);
    float4 a = rp[l], b = rp[64 + l];
    float ssq = dot4(a, a) + dot4(b, b);
#pragma unroll
    for (int m = 1; m < 64; m <<= 1) ssq += __shfl_xor(ssq, m);
    float inv = 1.0f / fmaxf(sqrtf(ssq), 1e-12f);
    a.x *= inv; a.y *= inv; a.z *= inv; a.w *= inv;
    b.x *= inv; b.y *= inv; b.z *= inv; b.w *= inv;
    ushort4 ua; ua.x = f2b(a.x); ua.y = f2b(a.y); ua.z = f2b(a.z); ua.w = f2b(a.w);
    ushort4 ub; ub.x = f2b(b.x); ub.y = f2b(b.y); ub.z = f2b(b.z); ub.w = f2b(b.w);
    ushort4* obp = (ushort4*)(wb + (size_t)row * D_K);
    obp[l] = ua; obp[64 + l] = ub;
}

// ------------- kernel C: disc loss partial + exact target logit -------------
__global__ void disc_kernel(const float* __restrict__ xn,
                            const int* __restrict__ target,
                            const float* __restrict__ ida,
                            const float* __restrict__ bmat,
                            float* __restrict__ sums,
                            float* __restrict__ tlogit) {
    int row = blockIdx.x * 4 + (threadIdx.x >> 6);
    int l = threadIdx.x & 63;
    long t = (long)target[row];
    const float4* xp = (const float4*)(xn + (size_t)row * D_K);
    const float4* wp = (const float4*)(ida + (size_t)t * D_K);
    const float4* bp = (const float4*)(bmat + (size_t)t * D_K);
    float4 x0 = xp[l], x1 = xp[64 + l];
    float4 w0 = wp[l], w1 = wp[64 + l];
    float4 b0 = bp[l], b1 = bp[64 + l];
    float wssq = dot4(w0, w0) + dot4(w1, w1);
    float bssq = dot4(b0, b0) + dot4(b1, b1);
#pragma unroll
    for (int m = 1; m < 64; m <<= 1) {
        wssq += __shfl_xor(wssq, m);
        bssq += __shfl_xor(bssq, m);
    }
    float winv = 1.0f / fmaxf(sqrtf(wssq), 1e-12f);
    float btn = sqrtf(bssq);
    float cs = fminf(btn, 0.05f) / fmaxf(btn, 1e-12f);

    float xs[8] = {x0.x, x0.y, x0.z, x0.w, x1.x, x1.y, x1.z, x1.w};
    float wv[8] = {w0.x, w0.y, w0.z, w0.w, w1.x, w1.y, w1.z, w1.w};
    float bv[8] = {b0.x, b0.y, b0.z, b0.w, b1.x, b1.y, b1.z, b1.w};
    float rss = 0.0f, dt = 0.0f;
#pragma unroll
    for (int i = 0; i < 8; ++i) {
        float wn = wv[i] * winv;
        float d = xs[i] - wn;
        float r = d - bv[i] * cs;
        rss += r * r;
        dt += xs[i] * wn;
    }
#pragma unroll
    for (int m = 1; m < 64; m <<= 1) {
        rss += __shfl_xor(rss, m);
        dt += __shfl_xor(dt, m);
    }
    if (l == 0) {
        atomicAdd(&sums[0], sqrtf(rss));
        tlogit[row] = SCALE_F * dt;
    }
}

// ------------- kernel D: bf16 MFMA GEMM with fused tile-LSE epilogue -------------
__global__ __launch_bounds__(256) void gemm_lse_kernel(const ushort* __restrict__ A,
                                                       const ushort* __restrict__ W,
                                                       float* __restrict__ pm,
                                                       float* __restrict__ pse) {
    __shared__ ushort As[BM * BK];
    __shared__ ushort Bs[BN * BK];
    __shared__ float smx[2][BM];
    __shared__ float sse[2][BM];

    int tid = threadIdx.x;
    int wave = tid >> 6, l = tid & 63;
    int wm = wave >> 1, wn = wave & 1;
    int m0 = blockIdx.x * BM;
    int nt = blockIdx.y, n0 = nt * BN;
    int sr = l >> 2;          // row within 16-row staging chunk
    int sc = (l & 3) * 8;     // k-element offset of this lane's 16B

    f32x4 zero4 = {0.0f, 0.0f, 0.0f, 0.0f};
    f32x4 acc[4][4];
#pragma unroll
    for (int i = 0; i < 4; ++i)
#pragma unroll
        for (int j = 0; j < 4; ++j) acc[i][j] = zero4;

    for (int kt = 0; kt < D_K; kt += BK) {
#pragma unroll
        for (int i = 0; i < 2; ++i) {
            int rb = i * 64 + wave * 16;
            const ushort* ga = A + (size_t)(m0 + rb + sr) * D_K + kt + sc;
            __builtin_amdgcn_global_load_lds(
                (const __attribute__((address_space(1))) void*)ga,
                (__attribute__((address_space(3))) void*)&As[rb * BK], 16, 0, 0);
            int rn = n0 + rb + sr;
            rn = rn < C_N ? rn : C_N - 1;
            const ushort* gb = W + (size_t)rn * D_K + kt + sc;
            __builtin_amdgcn_global_load_lds(
                (const __attribute__((address_space(1))) void*)gb,
                (__attribute__((address_space(3))) void*)&Bs[rb * BK], 16, 0, 0);
        }
        __syncthreads();

        short8 af[4], bfr[4];
#pragma unroll
        for (int mi = 0; mi < 4; ++mi)
            af[mi] = *(const short8*)&As[(wm * 64 + mi * 16 + (l & 15)) * BK + (l >> 4) * 8];
#pragma unroll
        for (int ni = 0; ni < 4; ++ni)
            bfr[ni] = *(const short8*)&Bs[(wn * 64 + ni * 16 + (l & 15)) * BK + (l >> 4) * 8];
#pragma unroll
        for (int mi = 0; mi < 4; ++mi)
#pragma unroll
            for (int ni = 0; ni < 4; ++ni)
                acc[mi][ni] = __builtin_amdgcn_mfma_f32_16x16x32_bf16(af[mi], bfr[ni], acc[mi][ni], 0, 0, 0);
        __syncthreads();
    }

    // epilogue: per-row (within this tile) max and sum(exp)
    int cl = l & 15, hi = l >> 4;
#pragma unroll
    for (int mi = 0; mi < 4; ++mi) {
#pragma unroll
        for (int j = 0; j < 4; ++j) {
            float s[4];
#pragma unroll
            for (int ni = 0; ni < 4; ++ni) {
                int cg = n0 + wn * 64 + ni * 16 + cl;
                s[ni] = (cg < C_N) ? acc[mi][ni][j] * SCALE_F : -INFINITY;
            }
            float mx = fmaxf(fmaxf(s[0], s[1]), fmaxf(s[2], s[3]));
#pragma unroll
            for (int xm = 1; xm < 16; xm <<= 1) mx = fmaxf(mx, __shfl_xor(mx, xm));
            float se = 0.0f;
#pragma unroll
            for (int ni = 0; ni < 4; ++ni)
                se += (s[ni] > -INFINITY) ? __expf(s[ni] - mx) : 0.0f;
#pragma unroll
            for (int xm = 1; xm < 16; xm <<= 1) se += __shfl_xor(se, xm);
            if (cl == 0) {
                int r = wm * 64 + mi * 16 + hi * 4 + j;
                smx[wn][r] = mx;
                sse[wn][r] = se;
            }
        }
    }
    __syncthreads();
    if (tid < BM) {
        float ma = smx[0][tid], mb = smx[1][tid];
        float mm = fmaxf(ma, mb);
        float se = 0.0f;
        if (ma > -INFINITY) se += sse[0][tid] * __expf(ma - mm);
        if (mb > -INFINITY) se += sse[1][tid] * __expf(mb - mm);
        size_t idx = (size_t)(m0 + tid) * NT_ + nt;
        pm[idx] = mm;
        pse[idx] = se;
    }
}

// ------------- kernel E: combine per-row partials -> nll, accumulate -------------
__global__ void row_lse_kernel(const float* __restrict__ pm,
                               const float* __restrict__ pse,
                               const float* __restrict__ tlogit,
                               float* __restrict__ sums) {
    int row = blockIdx.x;
    int tid = threadIdx.x;
    __shared__ float redm[4];
    __shared__ float reds[4];
    const float* pmr = pm + (size_t)row * NT_;
    const float* pser = pse + (size_t)row * NT_;

    float lm = -INFINITY;
    for (int t = tid; t < NT_; t += 256) lm = fmaxf(lm, pmr[t]);
#pragma unroll
    for (int xm = 1; xm < 64; xm <<= 1) lm = fmaxf(lm, __shfl_xor(lm, xm));
    if ((tid & 63) == 0) redm[tid >> 6] = lm;
    __syncthreads();
    float M = fmaxf(fmaxf(redm[0], redm[1]), fmaxf(redm[2], redm[3]));

    float ls = 0.0f;
    for (int t = tid; t < NT_; t += 256) {
        float m = pmr[t];
        if (m > -INFINITY) ls += pser[t] * __expf(m - M);
    }
#pragma unroll
    for (int xm = 1; xm < 64; xm <<= 1) ls += __shfl_xor(ls, xm);
    if ((tid & 63) == 0) reds[tid >> 6] = ls;
    __syncthreads();
    if (tid == 0) {
        float S = reds[0] + reds[1] + reds[2] + reds[3];
        float lse = M + logf(S);
        float st = tlogit[row];
        // replace exp(st) by exp(st - 64*margin) inside the lse
        float corr = __expf(st - lse) * (__expf(-SCALE_F * MARGIN_F) - 1.0f);
        float lse2 = lse + log1pf(corr);
        float nll = lse2 - (st - SCALE_F * MARGIN_F);
        atomicAdd(&sums[1], nll);
    }
}

// ------------- kernel F: finalize scalar output -------------
__global__ void finalize_kernel(const float* __restrict__ sums, float* __restrict__ out) {
    float disc = sums[0] * (1.0f / B_N);
    float logp = sums[1] * (1.0f / B_N);
    float p = __expf(-logp);
    float om = 1.0f - p;
    out[0] = 0.4f * disc + om * om * logp;
}

extern "C" void kernel_launch(void* const* d_in, const int* in_sizes, int n_in,
                              void* d_out, int out_size, void* d_ws, size_t ws_size,
                              hipStream_t stream) {
    const float* x = (const float*)d_in[0];
    const int* target = (const int*)d_in[1];
    const float* ida = (const float*)d_in[2];
    const float* bmat = (const float*)d_in[3];
    float* out = (float*)d_out;

    char* ws = (char*)d_ws;
    size_t off = 0;
    float* xn = (float*)(ws + off);      off += (size_t)B_N * D_K * 4;   // 2 MB
    ushort* xnb = (ushort*)(ws + off);   off += (size_t)B_N * D_K * 2;   // 1 MB
    ushort* wbf = (ushort*)(ws + off);   off += (size_t)C_N * D_K * 2;   // 102.4 MB
    float* pm = (float*)(ws + off);      off += (size_t)B_N * NT_ * 4;   // 3.2 MB
    float* pse = (float*)(ws + off);     off += (size_t)B_N * NT_ * 4;   // 3.2 MB
    float* tlogit = (float*)(ws + off);  off += (size_t)B_N * 4;
    float* sums = (float*)(ws + off);    off += 256;

    hipMemsetAsync(sums, 0, 2 * sizeof(float), stream);

    norm_x_kernel<<<B_N / 4, 256, 0, stream>>>(x, xn, xnb);
    norm_w_kernel<<<C_N / 4, 256, 0, stream>>>(ida, wbf);
    disc_kernel<<<B_N / 4, 256, 0, stream>>>(xn, target, ida, bmat, sums, tlogit);
    gemm_lse_kernel<<<dim3(B_N / BM, NT_), 256, 0, stream>>>(xnb, wbf, pm, pse);
    row_lse_kernel<<<B_N, 256, 0, stream>>>(pm, pse, tlogit, sums);
    finalize_kernel<<<1, 1, 0, stream>>>(sums, out);
}